// Round 1
// baseline (723.242 us; speedup 1.0000x reference)
//
#include <hip/hip_runtime.h>
#include <math.h>

#define NHEAD 8
#define DIM   32
#define TOPK  8
#define TEMP  0.17677669529663687f   // 1/sqrt(32)

// Butterfly argmax over 32 lanes, tie-break: lowest index (matches jax.lax.top_k)
__device__ __forceinline__ void argmax32(float& v, int& i) {
#pragma unroll
  for (int off = 16; off >= 1; off >>= 1) {
    float ov = __shfl_xor(v, off, 32);
    int   oi = __shfl_xor(i, off, 32);
    if (ov > v || (ov == v && oi < i)) { v = ov; i = oi; }
  }
}

// ---------------- Level 0: dense attention over 16x16 coarse grid ----------
// grid: B*256 blocks, 256 threads = 8 heads x 32 lanes
__global__ __launch_bounds__(256) void l0_kernel(
    const float* __restrict__ Q, const float* __restrict__ K, const float* __restrict__ V,
    float* __restrict__ msg0, int* __restrict__ tki0, float* __restrict__ tkp0)
{
  const int b = blockIdx.x >> 8;
  const int l = blockIdx.x & 255;
  const int t = threadIdx.x;
  const int h = t >> 5, lane = t & 31;

  __shared__ float q_s[NHEAD][DIM];
  __shared__ float probs[NHEAD][256];
  __shared__ int   tk_i[NHEAD][TOPK];
  __shared__ float tk_p[NHEAD][TOPK];

  const size_t cb = ((size_t)(b * 256 + h * 32)) * 256;  // [b, c=h*32, :] base
  q_s[h][lane] = Q[cb + (size_t)lane * 256 + l];
  __syncthreads();

  // scores: lane owns s = j*32+lane, j=0..7
  float sc[8];
#pragma unroll
  for (int j = 0; j < 8; ++j) sc[j] = 0.f;
  for (int d = 0; d < 32; ++d) {
    const float qd = q_s[h][d];
    const float* kr = K + cb + (size_t)d * 256;
#pragma unroll
    for (int j = 0; j < 8; ++j) sc[j] += qd * kr[j * 32 + lane];
  }
#pragma unroll
  for (int j = 0; j < 8; ++j) sc[j] *= TEMP;

  // softmax over all 256
  float mx = sc[0];
#pragma unroll
  for (int j = 1; j < 8; ++j) mx = fmaxf(mx, sc[j]);
#pragma unroll
  for (int off = 16; off >= 1; off >>= 1) mx = fmaxf(mx, __shfl_xor(mx, off, 32));
  float ev[8]; float ssum = 0.f;
#pragma unroll
  for (int j = 0; j < 8; ++j) { ev[j] = expf(sc[j] - mx); ssum += ev[j]; }
#pragma unroll
  for (int off = 16; off >= 1; off >>= 1) ssum += __shfl_xor(ssum, off, 32);
  const float inv = 1.f / ssum;
#pragma unroll
  for (int j = 0; j < 8; ++j) probs[h][j * 32 + lane] = ev[j] * inv;

  // top-8 (on scaled scores; monotone with probs)
  int msk = 0;
#pragma unroll
  for (int k = 0; k < TOPK; ++k) {
    float bv = -INFINITY; int bi = 1 << 30;
#pragma unroll
    for (int j = 0; j < 8; ++j) {
      if (!((msk >> j) & 1)) {
        int gi = j * 32 + lane;
        if (sc[j] > bv || (sc[j] == bv && gi < bi)) { bv = sc[j]; bi = gi; }
      }
    }
    argmax32(bv, bi);
    if ((bi & 31) == lane) msk |= 1 << (bi >> 5);
    if (lane == 0) { tk_i[h][k] = bi; tk_p[h][k] = expf(bv - mx) * inv; }
  }
  __syncthreads();

  // message: lane = d
  float acc = 0.f;
  const float* vr = V + cb + (size_t)lane * 256;
  for (int s = 0; s < 256; ++s) acc += probs[h][s] * vr[s];
#pragma unroll
  for (int k = 0; k < TOPK; ++k) acc -= tk_p[h][k] * vr[tk_i[h][k]];

  msg0[((size_t)(b * 256 + l) * NHEAD + h) * DIM + lane] = acc;
  if (lane < TOPK) {
    const int o = ((b * 256 + l) * TOPK + lane) * NHEAD + h;
    tki0[o] = tk_i[h][lane];
    tkp0[o] = tk_p[h][lane];
  }
}

// ---------------- Refinement level (W=32 with topk out, W=64 final) --------
// grid: B * (W/2)^2 blocks, 256 threads = 8 heads x 32 lanes (lane = entry e=k*4+f)
template <int W, bool HAS_TOPK>
__global__ __launch_bounds__(256) void refine_kernel(
    const float* __restrict__ Q, const float* __restrict__ K, const float* __restrict__ V,
    const float* __restrict__ msgp, const int* __restrict__ tkip, const float* __restrict__ tkpp,
    float* __restrict__ msgo, int* __restrict__ tkio, float* __restrict__ tkpo)
{
  constexpr int S  = W * W;
  constexpr int HW = W / 2;       // prev-level token grid dim
  constexpr int Lp = HW * HW;
  const int b = blockIdx.x / Lp;
  const int l = blockIdx.x % Lp;
  const int gr = l / HW, gc = l % HW;
  const int t = threadIdx.x;
  const int h = t >> 5, lane = t & 31;

  __shared__ float q_s[4][NHEAD][DIM];
  __shared__ int   cidx_s[NHEAD][32];
  __shared__ float w_s[NHEAD][32];

  const size_t cbase = ((size_t)(b * 256 + h * 32)) * S;

  // q for the 4 fine children of this coarse cell
#pragma unroll
  for (int wq = 0; wq < 4; ++wq) {
    const int rr = 2 * gr + (wq >> 1), cc = 2 * gc + (wq & 1);
    q_s[wq][h][lane] = Q[cbase + (size_t)lane * S + rr * W + cc];
  }

  // gathered child index + coarse score for entry e = k*4+f
  const int k0 = lane >> 2, f = lane & 3;
  const int pofs = ((b * Lp + l) * TOPK + k0) * NHEAD + h;
  const int ti = tkip[pofs];
  const float csc = tkpp[pofs];
  cidx_s[h][lane] = ((ti / HW) * 2 + (f >> 1)) * W + ((ti % HW) * 2 + (f & 1));
  __syncthreads();
  const int cidx = cidx_s[h][lane];

  // key child vector in registers
  float kv[DIM];
#pragma unroll
  for (int d = 0; d < DIM; ++d) kv[d] = K[cbase + (size_t)d * S + cidx];

  const float mprev = msgp[((size_t)(b * Lp + l) * NHEAD + h) * DIM + lane];

  for (int wq = 0; wq < 4; ++wq) {
    float qk = 0.f;
#pragma unroll
    for (int d = 0; d < DIM; ++d) qk += q_s[wq][h][d] * kv[d];
    const float v = TEMP * qk;

    // softmax over 4 children (f groups of 4 lanes)
    float m1 = fmaxf(v, __shfl_xor(v, 1, 4));
    float m2 = fmaxf(m1, __shfl_xor(m1, 2, 4));
    float ex = expf(v - m2);
    float s1 = ex + __shfl_xor(ex, 1, 4);
    float s2 = s1 + __shfl_xor(s1, 2, 4);
    const float A = (ex / s2) * csc;

    float sel_v[TOPK]; int sel_e[TOPK];
    if constexpr (HAS_TOPK) {
      bool mymask = false;
#pragma unroll
      for (int k = 0; k < TOPK; ++k) {
        float bv = mymask ? -INFINITY : A;
        int bi = lane;
        argmax32(bv, bi);
        sel_v[k] = bv; sel_e[k] = bi;
        if (bi == lane) mymask = true;
      }
    }

    w_s[h][lane] = A;
    __syncthreads();

    // message for this wq; lane = d
    float acc = 0.f;
    const float* vcol = V + cbase + (size_t)lane * S;
#pragma unroll
    for (int e = 0; e < 32; ++e) acc += w_s[h][e] * vcol[cidx_s[h][e]];
    if constexpr (HAS_TOPK) {
#pragma unroll
      for (int k = 0; k < TOPK; ++k) acc -= sel_v[k] * vcol[cidx_s[h][sel_e[k]]];
    }
    const float outv = mprev + acc;

    const int rr = 2 * gr + (wq >> 1), cc = 2 * gc + (wq & 1);
    const int tok = rr * W + cc;
    msgo[((size_t)(b * S + tok) * NHEAD + h) * DIM + lane] = outv;
    if constexpr (HAS_TOPK) {
      if (lane == 0) {
#pragma unroll
        for (int k = 0; k < TOPK; ++k) {
          const int o = ((b * S + tok) * TOPK + k) * NHEAD + h;
          tkio[o] = cidx_s[h][sel_e[k]];
          tkpo[o] = sel_v[k];
        }
      }
    }
    __syncthreads();  // w_s reused next wq
  }
}

extern "C" void kernel_launch(void* const* d_in, const int* in_sizes, int n_in,
                              void* d_out, int out_size, void* d_ws, size_t ws_size,
                              hipStream_t stream)
{
  const float* Q0 = (const float*)d_in[0];  // 64x64 (fine)
  const float* Q1 = (const float*)d_in[1];  // 32x32
  const float* Q2 = (const float*)d_in[2];  // 16x16 (coarse)
  const float* K0 = (const float*)d_in[3];
  const float* K1 = (const float*)d_in[4];
  const float* K2 = (const float*)d_in[5];
  const float* V0 = (const float*)d_in[6];
  const float* V1 = (const float*)d_in[7];
  const float* V2 = (const float*)d_in[8];
  float* out = (float*)d_out;

  // workspace layout (floats/ints, ~7.9 MB total)
  float* msg0 = (float*)d_ws;                        // 4*256*8*32
  int*   tki0 = (int*)(msg0 + 4 * 256 * 8 * 32);     // 4*256*8*8
  float* tkp0 = (float*)(tki0 + 4 * 256 * 8 * 8);    // 4*256*8*8
  float* msg1 = tkp0 + 4 * 256 * 8 * 8;              // 4*1024*8*32
  int*   tki1 = (int*)(msg1 + 4 * 1024 * 8 * 32);    // 4*1024*8*8
  float* tkp1 = (float*)(tki1 + 4 * 1024 * 8 * 8);   // 4*1024*8*8

  hipLaunchKernelGGL(l0_kernel, dim3(4 * 256), dim3(256), 0, stream,
                     Q2, K2, V2, msg0, tki0, tkp0);
  hipLaunchKernelGGL((refine_kernel<32, true>), dim3(4 * 256), dim3(256), 0, stream,
                     Q1, K1, V1, msg0, tki0, tkp0, msg1, tki1, tkp1);
  hipLaunchKernelGGL((refine_kernel<64, false>), dim3(4 * 1024), dim3(256), 0, stream,
                     Q0, K0, V0, msg1, tki1, tkp1, out, nullptr, nullptr);
}

// Round 2
// 144.579 us; speedup vs baseline: 5.0024x; 5.0024x over previous
//
#include <hip/hip_runtime.h>
#include <math.h>

#define NHEAD 8
#define DIM   32
#define TOPK  8
#define TEMP  0.17677669529663687f   // 1/sqrt(32)
#define BATCH 4

// Butterfly argmax over 32 lanes, tie-break: lowest index (matches jax.lax.top_k)
__device__ __forceinline__ void argmax32(float& v, int& i) {
#pragma unroll
  for (int off = 16; off >= 1; off >>= 1) {
    float ov = __shfl_xor(v, off, 32);
    int   oi = __shfl_xor(i, off, 32);
    if (ov > v || (ov == v && oi < i)) { v = ov; i = oi; }
  }
}

// ---------------- Transpose [B, 256, S] -> [B, S, 256] for Q,K,V ----------
template <int S>
__global__ __launch_bounds__(256) void transpose_qkv(
    const float* __restrict__ Q, const float* __restrict__ K, const float* __restrict__ V,
    float* __restrict__ Qt, float* __restrict__ Kt, float* __restrict__ Vt)
{
  __shared__ float tile[32][33];
  const int z = blockIdx.z;           // z = tensor*B + b
  const int b = z & (BATCH - 1);
  const int tsel = z >> 2;
  const float* in = tsel == 0 ? Q : tsel == 1 ? K : V;
  float* out      = tsel == 0 ? Qt : tsel == 1 ? Kt : Vt;
  const int s0 = blockIdx.x * 32;
  const int c0 = blockIdx.y * 32;
  const int tx = threadIdx.x & 31;
  const int ty = threadIdx.x >> 5;    // 0..7
  const size_t ibase = ((size_t)b * 256 + c0) * S + s0;
#pragma unroll
  for (int i = ty; i < 32; i += 8)
    tile[i][tx] = in[ibase + (size_t)i * S + tx];
  __syncthreads();
  const size_t obase = ((size_t)b * S + s0) * 256 + c0;
#pragma unroll
  for (int i = ty; i < 32; i += 8)
    out[obase + (size_t)i * 256 + tx] = tile[tx][i];
}

// ---------------- Level 0: dense attention over 16x16 coarse grid ----------
// grid: B*256 blocks, 256 threads = 8 heads x 32 lanes
__global__ __launch_bounds__(256) void l0_kernel(
    const float* __restrict__ Q, const float* __restrict__ K, const float* __restrict__ V,
    float* __restrict__ msg0, int* __restrict__ tki0, float* __restrict__ tkp0)
{
  const int b = blockIdx.x >> 8;
  const int l = blockIdx.x & 255;
  const int t = threadIdx.x;
  const int h = t >> 5, lane = t & 31;

  __shared__ float q_s[NHEAD][DIM];
  __shared__ float probs[NHEAD][256];
  __shared__ int   tk_i[NHEAD][TOPK];
  __shared__ float tk_p[NHEAD][TOPK];

  const size_t cb = ((size_t)(b * 256 + h * 32)) * 256;  // [b, c=h*32, :] base
  q_s[h][lane] = Q[cb + (size_t)lane * 256 + l];

  // scores: lane owns s = j*32+lane, j=0..7
  float sc[8];
#pragma unroll
  for (int j = 0; j < 8; ++j) sc[j] = 0.f;
  for (int d = 0; d < 32; ++d) {
    const float qd = q_s[h][d];
    const float* kr = K + cb + (size_t)d * 256;
#pragma unroll
    for (int j = 0; j < 8; ++j) sc[j] += qd * kr[j * 32 + lane];
  }
#pragma unroll
  for (int j = 0; j < 8; ++j) sc[j] *= TEMP;

  // softmax over all 256
  float mx = sc[0];
#pragma unroll
  for (int j = 1; j < 8; ++j) mx = fmaxf(mx, sc[j]);
#pragma unroll
  for (int off = 16; off >= 1; off >>= 1) mx = fmaxf(mx, __shfl_xor(mx, off, 32));
  float ev[8]; float ssum = 0.f;
#pragma unroll
  for (int j = 0; j < 8; ++j) { ev[j] = expf(sc[j] - mx); ssum += ev[j]; }
#pragma unroll
  for (int off = 16; off >= 1; off >>= 1) ssum += __shfl_xor(ssum, off, 32);
  const float inv = 1.f / ssum;

  // top-8 (on scaled scores; monotone with probs)
  int msk = 0;
#pragma unroll
  for (int k = 0; k < TOPK; ++k) {
    float bv = -INFINITY; int bi = 1 << 30;
#pragma unroll
    for (int j = 0; j < 8; ++j) {
      if (!((msk >> j) & 1)) {
        int gi = j * 32 + lane;
        if (sc[j] > bv || (sc[j] == bv && gi < bi)) { bv = sc[j]; bi = gi; }
      }
    }
    argmax32(bv, bi);
    if ((bi & 31) == lane) msk |= 1 << (bi >> 5);
    if (lane == 0) { tk_i[h][k] = bi; tk_p[h][k] = expf(bv - mx) * inv; }
  }

  // masked probabilities (topk entries zeroed; equals sum-then-subtract up to fp rounding)
#pragma unroll
  for (int j = 0; j < 8; ++j)
    probs[h][j * 32 + lane] = ((msk >> j) & 1) ? 0.f : ev[j] * inv;
  __syncthreads();

  // message: lane = d
  float acc = 0.f;
  const float* vr = V + cb + (size_t)lane * 256;
  for (int s = 0; s < 256; ++s) acc += probs[h][s] * vr[s];

  msg0[((size_t)(b * 256 + l) * NHEAD + h) * DIM + lane] = acc;
  if (lane < TOPK) {
    const int o = ((b * 256 + l) * TOPK + lane) * NHEAD + h;
    tki0[o] = tk_i[h][lane];
    tkp0[o] = tk_p[h][lane];
  }
}

// ---------------- Token-major refinement (fast path) -----------------------
// Qt/Kt/Vt are [b, S, 256] (token-major). grid: B*(W/2)^2 blocks, 256 thr.
template <int W, bool HAS_TOPK>
__global__ __launch_bounds__(256) void refine_tm_kernel(
    const float* __restrict__ Qt, const float* __restrict__ Kt, const float* __restrict__ Vt,
    const float* __restrict__ msgp, const int* __restrict__ tkip, const float* __restrict__ tkpp,
    float* __restrict__ msgo, int* __restrict__ tkio, float* __restrict__ tkpo)
{
  constexpr int S  = W * W;
  constexpr int HW = W / 2;
  constexpr int Lp = HW * HW;
  const int b = blockIdx.x / Lp;
  const int l = blockIdx.x % Lp;
  const int gr = l / HW, gc = l % HW;
  const int t = threadIdx.x;
  const int h = t >> 5, lane = t & 31;

  __shared__ float q_s[NHEAD][4][DIM];
  __shared__ int   cidx_s[NHEAD][32];
  __shared__ float w_s[NHEAD][32];

  // entry e = lane: child index + coarse score
  const int k0 = lane >> 2, f = lane & 3;
  const int pofs = ((b * Lp + l) * TOPK + k0) * NHEAD + h;
  const int ti = tkip[pofs];
  const float csc = tkpp[pofs];
  const int cidx = ((ti / HW) * 2 + (f >> 1)) * W + ((ti % HW) * 2 + (f & 1));
  cidx_s[h][lane] = cidx;
  // all shared arrays are per-head (within one half-wave) -> no barriers needed

  // Q for the 4 fine children (coalesced)
#pragma unroll
  for (int wq = 0; wq < 4; ++wq) {
    const int rr = 2 * gr + (wq >> 1), cc = 2 * gc + (wq & 1);
    q_s[h][wq][lane] = Qt[((size_t)b * S + rr * W + cc) * 256 + h * DIM + lane];
  }

  // K token for entry e = lane: contiguous 128B via float4
  float kv[DIM];
  {
    const float4* kp = (const float4*)(Kt + ((size_t)b * S + cidx) * 256 + h * DIM);
#pragma unroll
    for (int j = 0; j < 8; ++j) {
      const float4 v4 = kp[j];
      kv[4 * j] = v4.x; kv[4 * j + 1] = v4.y; kv[4 * j + 2] = v4.z; kv[4 * j + 3] = v4.w;
    }
  }

  // V: lane = d role; vv[e] loaded coalesced across lanes, once (not per wq)
  float vv[32];
#pragma unroll
  for (int e = 0; e < 32; ++e)
    vv[e] = Vt[((size_t)b * S + cidx_s[h][e]) * 256 + h * DIM + lane];

  const float mprev = msgp[((size_t)(b * Lp + l) * NHEAD + h) * DIM + lane];

#pragma unroll
  for (int wq = 0; wq < 4; ++wq) {
    float qk = 0.f;
#pragma unroll
    for (int d = 0; d < DIM; ++d) qk += q_s[h][wq][d] * kv[d];
    const float sval = TEMP * qk;

    // softmax over the 4 children (f groups of 4 lanes)
    float m1 = fmaxf(sval, __shfl_xor(sval, 1, 4));
    float m2 = fmaxf(m1, __shfl_xor(m1, 2, 4));
    float ex = expf(sval - m2);
    float s1 = ex + __shfl_xor(ex, 1, 4);
    float s2 = s1 + __shfl_xor(s1, 2, 4);
    const float A = (ex / s2) * csc;

    float Am = A;             // masked weight for the message
    int   my_e = 0; float my_v = 0.f;   // this lane's rank-(lane) topk entry
    if constexpr (HAS_TOPK) {
      bool mymask = false;
#pragma unroll
      for (int k = 0; k < TOPK; ++k) {
        float bv = mymask ? -INFINITY : A;
        int bi = lane;
        argmax32(bv, bi);
        if (bi == lane) mymask = true;
        if (lane == k) { my_e = bi; my_v = bv; }   // static condition per unrolled k
      }
      if (mymask) Am = 0.f;
    }

    w_s[h][lane] = Am;
    // same half-wave -> lockstep; no barrier

    float acc = 0.f;
#pragma unroll
    for (int e = 0; e < 32; ++e) acc += w_s[h][e] * vv[e];
    const float outv = mprev + acc;

    const int rr = 2 * gr + (wq >> 1), cc = 2 * gc + (wq & 1);
    const int tok = rr * W + cc;
    msgo[((size_t)(b * S + tok) * NHEAD + h) * DIM + lane] = outv;
    if constexpr (HAS_TOPK) {
      if (lane < TOPK) {
        const int o = ((b * S + tok) * TOPK + lane) * NHEAD + h;
        tkio[o] = cidx_s[h][my_e];
        tkpo[o] = my_v;
      }
    }
  }
}

// ---------------- Channel-major refinement (fallback if ws too small) ------
template <int W, bool HAS_TOPK>
__global__ __launch_bounds__(256) void refine_cm_kernel(
    const float* __restrict__ Q, const float* __restrict__ K, const float* __restrict__ V,
    const float* __restrict__ msgp, const int* __restrict__ tkip, const float* __restrict__ tkpp,
    float* __restrict__ msgo, int* __restrict__ tkio, float* __restrict__ tkpo)
{
  constexpr int S  = W * W;
  constexpr int HW = W / 2;
  constexpr int Lp = HW * HW;
  const int b = blockIdx.x / Lp;
  const int l = blockIdx.x % Lp;
  const int gr = l / HW, gc = l % HW;
  const int t = threadIdx.x;
  const int h = t >> 5, lane = t & 31;

  __shared__ float q_s[4][NHEAD][DIM];
  __shared__ int   cidx_s[NHEAD][32];
  __shared__ float w_s[NHEAD][32];

  const size_t cbase = ((size_t)(b * 256 + h * 32)) * S;

#pragma unroll
  for (int wq = 0; wq < 4; ++wq) {
    const int rr = 2 * gr + (wq >> 1), cc = 2 * gc + (wq & 1);
    q_s[wq][h][lane] = Q[cbase + (size_t)lane * S + rr * W + cc];
  }

  const int k0 = lane >> 2, f = lane & 3;
  const int pofs = ((b * Lp + l) * TOPK + k0) * NHEAD + h;
  const int ti = tkip[pofs];
  const float csc = tkpp[pofs];
  cidx_s[h][lane] = ((ti / HW) * 2 + (f >> 1)) * W + ((ti % HW) * 2 + (f & 1));
  const int cidx = cidx_s[h][lane];

  float kv[DIM];
#pragma unroll
  for (int d = 0; d < DIM; ++d) kv[d] = K[cbase + (size_t)d * S + cidx];

  const float mprev = msgp[((size_t)(b * Lp + l) * NHEAD + h) * DIM + lane];

  for (int wq = 0; wq < 4; ++wq) {
    float qk = 0.f;
#pragma unroll
    for (int d = 0; d < DIM; ++d) qk += q_s[wq][h][d] * kv[d];
    const float v = TEMP * qk;

    float m1 = fmaxf(v, __shfl_xor(v, 1, 4));
    float m2 = fmaxf(m1, __shfl_xor(m1, 2, 4));
    float ex = expf(v - m2);
    float s1 = ex + __shfl_xor(ex, 1, 4);
    float s2 = s1 + __shfl_xor(s1, 2, 4);
    const float A = (ex / s2) * csc;

    float Am = A;
    int   my_e = 0; float my_v = 0.f;
    if constexpr (HAS_TOPK) {
      bool mymask = false;
#pragma unroll
      for (int k = 0; k < TOPK; ++k) {
        float bv = mymask ? -INFINITY : A;
        int bi = lane;
        argmax32(bv, bi);
        if (bi == lane) mymask = true;
        if (lane == k) { my_e = bi; my_v = bv; }
      }
      if (mymask) Am = 0.f;
    }

    w_s[h][lane] = Am;

    float acc = 0.f;
    const float* vcol = V + cbase + (size_t)lane * S;
#pragma unroll
    for (int e = 0; e < 32; ++e) acc += w_s[h][e] * vcol[cidx_s[h][e]];
    const float outv = mprev + acc;

    const int rr = 2 * gr + (wq >> 1), cc = 2 * gc + (wq & 1);
    const int tok = rr * W + cc;
    msgo[((size_t)(b * S + tok) * NHEAD + h) * DIM + lane] = outv;
    if constexpr (HAS_TOPK) {
      if (lane < TOPK) {
        const int o = ((b * S + tok) * TOPK + lane) * NHEAD + h;
        tkio[o] = cidx_s[h][my_e];
        tkpo[o] = my_v;
      }
    }
  }
}

extern "C" void kernel_launch(void* const* d_in, const int* in_sizes, int n_in,
                              void* d_out, int out_size, void* d_ws, size_t ws_size,
                              hipStream_t stream)
{
  const float* Q0 = (const float*)d_in[0];  // 64x64 (fine)
  const float* Q1 = (const float*)d_in[1];  // 32x32
  const float* Q2 = (const float*)d_in[2];  // 16x16 (coarse)
  const float* K0 = (const float*)d_in[3];
  const float* K1 = (const float*)d_in[4];
  const float* K2 = (const float*)d_in[5];
  const float* V0 = (const float*)d_in[6];
  const float* V1 = (const float*)d_in[7];
  const float* V2 = (const float*)d_in[8];
  float* out = (float*)d_out;

  // workspace layout (element counts)
  const size_t N_MSG0 = (size_t)BATCH * 256 * NHEAD * DIM;    // 262144
  const size_t N_TK0  = (size_t)BATCH * 256 * TOPK * NHEAD;   // 65536
  const size_t N_MSG1 = (size_t)BATCH * 1024 * NHEAD * DIM;   // 1048576
  const size_t N_TK1  = (size_t)BATCH * 1024 * TOPK * NHEAD;  // 262144
  const size_t N_T1   = (size_t)BATCH * 1024 * 256;           // 1048576 (per tensor, lvl 32x32)
  const size_t N_T0   = (size_t)BATCH * 4096 * 256;           // 4194304 (per tensor, lvl 64x64)

  float* p = (float*)d_ws;
  float* msg0 = p;            p += N_MSG0;
  int*   tki0 = (int*)p;      p += N_TK0;
  float* tkp0 = p;            p += N_TK0;
  float* msg1 = p;            p += N_MSG1;
  int*   tki1 = (int*)p;      p += N_TK1;
  float* tkp1 = p;            p += N_TK1;
  float* Qt1  = p;            p += N_T1;
  float* Kt1  = p;            p += N_T1;
  float* Vt1  = p;            p += N_T1;
  float* Qt0  = p;            p += N_T0;
  float* Kt0  = p;            p += N_T0;
  float* Vt0  = p;            p += N_T0;
  const size_t need_bytes = (size_t)(p - (float*)d_ws) * sizeof(float);

  hipLaunchKernelGGL(l0_kernel, dim3(BATCH * 256), dim3(256), 0, stream,
                     Q2, K2, V2, msg0, tki0, tkp0);

  if (ws_size >= need_bytes) {
    // fast path: token-major
    hipLaunchKernelGGL((transpose_qkv<1024>), dim3(32, 8, 3 * BATCH), dim3(256), 0, stream,
                       Q1, K1, V1, Qt1, Kt1, Vt1);
    hipLaunchKernelGGL((transpose_qkv<4096>), dim3(128, 8, 3 * BATCH), dim3(256), 0, stream,
                       Q0, K0, V0, Qt0, Kt0, Vt0);
    hipLaunchKernelGGL((refine_tm_kernel<32, true>), dim3(BATCH * 256), dim3(256), 0, stream,
                       Qt1, Kt1, Vt1, msg0, tki0, tkp0, msg1, tki1, tkp1);
    hipLaunchKernelGGL((refine_tm_kernel<64, false>), dim3(BATCH * 1024), dim3(256), 0, stream,
                       Qt0, Kt0, Vt0, msg1, tki1, tkp1, out, nullptr, nullptr);
  } else {
    // fallback: channel-major (round-1 structure)
    hipLaunchKernelGGL((refine_cm_kernel<32, true>), dim3(BATCH * 256), dim3(256), 0, stream,
                       Q1, K1, V1, msg0, tki0, tkp0, msg1, tki1, tkp1);
    hipLaunchKernelGGL((refine_cm_kernel<64, false>), dim3(BATCH * 1024), dim3(256), 0, stream,
                       Q0, K0, V0, msg1, tki1, tkp1, out, nullptr, nullptr);
  }
}